// Round 9
// baseline (482.695 us; speedup 1.0000x reference)
//
#include <hip/hip_runtime.h>
#include <stdint.h>
#include <math.h>

// Problem constants (hard-coded in reference)
#define NBBOX 8192
#define FDIM  4096
#define H1DIM 64
#define H2DIM 32
#define NW    16

typedef __attribute__((ext_vector_type(8))) _Float16 f16x8;
typedef __attribute__((ext_vector_type(4))) float    f32x4;

typedef __attribute__((address_space(1))) void* gptr_t;
typedef __attribute__((address_space(3))) void* lptr_t;

// async global->LDS, 16B per lane; LDS dest is wave-uniform base + lane*16
__device__ __forceinline__ void g2l16(const void* g, void* l) {
    __builtin_amdgcn_global_load_lds((gptr_t)(uintptr_t)g,
                                     (lptr_t)(uint32_t)(uintptr_t)l,
                                     16, 0, 0);
}

// DIY grid barrier for an exactly-co-resident 512-block grid (2/CU x 256 CU,
// guaranteed by launch_bounds(256,2) + 64KB LDS). Device-scope atomics +
// threadfence are sufficient cross-XCD [G16, m20]. One counter per site,
// zeroed by a captured hipMemsetAsync before each replay.
__device__ __forceinline__ void gbar(uint32_t* c) {
    __syncthreads();
    if (threadIdx.x == 0) {
        __threadfence();   // release: write back this block's stores (L2 wb)
        __hip_atomic_fetch_add(c, 1u, __ATOMIC_ACQ_REL, __HIP_MEMORY_SCOPE_AGENT);
        while (__hip_atomic_load(c, __ATOMIC_ACQUIRE, __HIP_MEMORY_SCOPE_AGENT) < 512u)
            __builtin_amdgcn_s_sleep(8);
        __threadfence();   // acquire: invalidate stale lines before reading others' data
    }
    __syncthreads();
}

// ================= single kernel, 512 blocks x 256 thr (standard launch) ==========
// phase 0: convert x f32->f16 (grid-stride) + gather/transpose W1[words]->bth
// phase 1: r2-verbatim GEMM(xh@bth^T)+bias+relu + fused layer2/3+sigmoid [83.5us body]
// phase 2: product over the 16 words
// gbar() between phases replaces 2 kernel launches (~25us each + fixed overhead).
__global__ __launch_bounds__(256, 2) void mono(
    const float* __restrict__ x, const int* __restrict__ words,
    const float* __restrict__ W1, const float* __restrict__ b1,
    const float* __restrict__ W2, const float* __restrict__ b2,
    const float* __restrict__ W3, const float* __restrict__ b3,
    _Float16* __restrict__ xh, uint32_t* __restrict__ bth_u32,
    float* __restrict__ sig, uint32_t* __restrict__ bar,
    float* __restrict__ out)
{
    __shared__ __align__(16) char smem[65536];
    const int bx  = blockIdx.x;
    const int tid = threadIdx.x;

    // ---------------- phase 0a: gather+transpose W1[words] -> bth ----------------
    // 16 words x 32 f-tiles = 512 blocks (grid is exactly 512)
    {
        uint32_t* t = (uint32_t*)smem;   // [c][f/2] pad 69 -> conflict-free (17.7 KB)
        const int wi = bx >> 5;
        const int ft = bx & 31;
        const int f0 = ft * 128;
        const int wd = words[wi];
        const int c    = tid & 63;
        const int fgrp = tid >> 6;       // 0..3

        const float* src = W1 + ((size_t)wd * FDIM + f0) * H1DIM + c;
#pragma unroll
        for (int p = 0; p < 16; ++p) {
            const int f = fgrp * 2 + p * 8;          // even f in 0..126
            float v0 = src[(size_t)f * H1DIM];        // coalesced (c contiguous)
            float v1 = src[(size_t)(f + 1) * H1DIM];
            union { _Float16 h[2]; uint32_t u; } pk;
            pk.h[0] = (_Float16)v0; pk.h[1] = (_Float16)v1;
            t[c * 69 + (f >> 1)] = pk.u;
        }
        __syncthreads();
#pragma unroll
        for (int p = 0; p < 16; ++p) {
            const int cc = p * 4 + (tid >> 6);
            const int fd = tid & 63;
            bth_u32[(size_t)(wi * 64 + cc) * (FDIM / 2) + ft * 64 + fd] = t[cc * 69 + fd];
        }
    }
    // ---------------- phase 0b: convert x -> xh (grid-stride, 32 iters) ----------------
    {
        const int base = bx * 256 + tid;     // 0..131071
#pragma unroll 4
        for (int it = 0; it < 32; ++it) {
            const size_t idx = ((size_t)(base + it * 131072)) * 8;
            float4 a = *(const float4*)(x + idx);
            float4 b = *(const float4*)(x + idx + 4);
            f16x8 h;
            h[0] = (_Float16)a.x; h[1] = (_Float16)a.y; h[2] = (_Float16)a.z; h[3] = (_Float16)a.w;
            h[4] = (_Float16)b.x; h[5] = (_Float16)b.y; h[6] = (_Float16)b.z; h[7] = (_Float16)b.w;
            *(f16x8*)(xh + idx) = h;
        }
    }
    gbar(bar);

    // ---------------- phase 1: GEMM + tail MLP (r2 body, verbatim) ----------------
    // 128x128 tile, BK=64, 4 waves, 16x16x32 MFMA, cross-kt double buffer,
    // ONE barrier per kt. mt=bx&63, nt=bx>>6 -> A-sharing blocks on one XCD.
    // LDS: buf c at smem+c*32768 {A at +0, B at +16384}; row r, 16B-slot s at
    // r*128+s*16 holding global chunk s^(r&7) (pre-swizzled g2l16 source).
    {
        const _Float16* bth = (const _Float16*)bth_u32;
        float* tile = (float*)smem;       // reused AFTER final k-loop barrier

        const int mt   = bx & 63;
        const int nt   = bx >> 6;
        const int w    = tid >> 6;
        const int lane = tid & 63;
        const int m0 = mt * 128, n0 = nt * 128;

        f32x4 acc[4][4] = {};

        const int lr = lane >> 3;            // row within 8-row group
        const int cg = (lane & 7) ^ lr;      // global 16B-chunk this lane fetches
        const _Float16* Ag = xh  + (size_t)(m0 + w * 32 + lr) * FDIM + cg * 8;
        const _Float16* Bg = bth + (size_t)(n0 + w * 32 + lr) * FDIM + cg * 8;
        const int ldst = w * 32 * 128;       // wave's LDS byte base

        const int wm = w >> 1, wn = w & 1;
        const int ml = lane & 15;
        const int qw = lane >> 4;

        // prologue: stage kt=0 into buffer 0
#pragma unroll
        for (int c = 0; c < 4; ++c) {
            g2l16(Ag + (size_t)(c * 8) * FDIM, smem + ldst + c * 1024);
            g2l16(Bg + (size_t)(c * 8) * FDIM, smem + 16384 + ldst + c * 1024);
        }
        __syncthreads();

        int cur = 0;
        for (int kt = 0; kt < 64; ++kt) {
            if (kt < 63) {
                const int nb = (cur ^ 1) * 32768;
                const size_t ko = (size_t)(kt + 1) * 64;
#pragma unroll
                for (int c = 0; c < 4; ++c) {
                    g2l16(Ag + (size_t)(c * 8) * FDIM + ko, smem + nb + ldst + c * 1024);
                    g2l16(Bg + (size_t)(c * 8) * FDIM + ko, smem + nb + 16384 + ldst + c * 1024);
                }
            }
            const _Float16* Ab = (const _Float16*)(smem + cur * 32768);
            const _Float16* Bb = (const _Float16*)(smem + cur * 32768 + 16384);
#pragma unroll
            for (int s = 0; s < 2; ++s) {
                f16x8 af[4], bfr[4];
#pragma unroll
                for (int i = 0; i < 4; ++i) {
                    const int ra = wm * 64 + i * 16 + ml;
                    af[i] = *(const f16x8*)&Ab[ra * 64 + (((s * 4 + qw) ^ (ml & 7)) * 8)];
                }
#pragma unroll
                for (int j = 0; j < 4; ++j) {
                    const int rb = wn * 64 + j * 16 + ml;
                    bfr[j] = *(const f16x8*)&Bb[rb * 64 + (((s * 4 + qw) ^ (ml & 7)) * 8)];
                }
#pragma unroll
                for (int i = 0; i < 4; ++i)
#pragma unroll
                    for (int j = 0; j < 4; ++j)
                        acc[i][j] = __builtin_amdgcn_mfma_f32_16x16x32_f16(af[i], bfr[j], acc[i][j], 0, 0, 0);
            }
            __syncthreads();   // drains g2l16 (vmcnt); guards swap; final: tile reuse
            cur ^= 1;
        }

        // ---- epilogue: bias+relu into wave-private swizzled LDS tile ----
        // C/D layout: col=lane&15, row=quad*4+reg  [m89-verified]
        const int q  = lane >> 4;
        const int wi = nt * 2 + wn;                                   // word slot 0..15
        const int wv = __builtin_amdgcn_readfirstlane(words[wi]);     // force SGPR
        float* tw = tile + w * 4096;                                  // [64 rows][64 k]

#pragma unroll
        for (int j = 0; j < 4; ++j) {
            const int col = j * 16 + ml;                              // k within word
            const float bias = b1[wv * H1DIM + col];
            const int c = col >> 2, e = col & 3;
#pragma unroll
            for (int i = 0; i < 4; ++i) {
#pragma unroll
                for (int r = 0; r < 4; ++r) {
                    const int row = i * 16 + q * 4 + r;               // local row 0..63
                    const int pos = ((c + row) & 7) | (c & 8);        // chunk swizzle
                    float v = acc[i][j][r] + bias;
                    tw[row * 64 + pos * 4 + e] = v > 0.f ? v : 0.f;
                }
            }
        }
        // wave-private LDS: no barrier needed (compiler inserts lgkmcnt waits)

        // ---- layer 2+3 + sigmoid, one row per lane ----
        const float* W2w = W2 + (size_t)wv * (H1DIM * H2DIM);
        float a2[H2DIM];
#pragma unroll
        for (int j = 0; j < H2DIM; ++j) a2[j] = 0.f;

#pragma unroll
        for (int c2 = 0; c2 < 16; ++c2) {
            const int pos = ((c2 + lane) & 7) | (c2 & 8);
            f32x4 h = *(const f32x4*)&tw[lane * 64 + pos * 4];
#pragma unroll
            for (int kk = 0; kk < 4; ++kk) {
                const float hv = h[kk];
                const int k = c2 * 4 + kk;
#pragma unroll
                for (int j = 0; j < H2DIM; ++j)
                    a2[j] = fmaf(hv, W2w[k * H2DIM + j], a2[j]);
            }
        }

        float logit = b3[wv];
#pragma unroll
        for (int j = 0; j < H2DIM; ++j) {
            float h2 = a2[j] + b2[wv * H2DIM + j];
            h2 = h2 > 0.f ? h2 : 0.f;
            logit = fmaf(h2, W3[wv * H2DIM + j], logit);
        }
        sig[(size_t)wi * NBBOX + m0 + wm * 64 + lane] = 1.f / (1.f + expf(-logit));
    }

    gbar(bar + 1);

    // ---------------- phase 2: product over words ----------------
    if (bx < NBBOX / 256) {
        const int r = bx * 256 + tid;
        float p = 1.f;
#pragma unroll
        for (int wi = 0; wi < NW; ++wi) p *= sig[(size_t)wi * NBBOX + r];
        out[r] = p;
    }
}

extern "C" void kernel_launch(void* const* d_in, const int* in_sizes, int n_in,
                              void* d_out, int out_size, void* d_ws, size_t ws_size,
                              hipStream_t stream)
{
    const float* x   = (const float*)d_in[1];
    const int* words = (const int*)  d_in[2];
    const float* W1  = (const float*)d_in[3];
    const float* b1  = (const float*)d_in[4];
    const float* W2  = (const float*)d_in[5];
    const float* b2  = (const float*)d_in[6];
    const float* W3  = (const float*)d_in[7];
    const float* b3  = (const float*)d_in[8];
    float* out = (float*)d_out;

    char* ws = (char*)d_ws;
    _Float16* xh  = (_Float16*)(ws);                           // 8192*4096*2 = 64 MiB
    uint32_t* bth = (uint32_t*)(ws + 67108864);                // 1024*4096*2 =  8 MiB
    float*    sig = (float*)   (ws + 67108864 + 8388608);      // 16*8192*4   = 512 KiB
    uint32_t* bar = (uint32_t*)(ws + 67108864 + 8388608 + 524288);   // 2 counters

    hipMemsetAsync(bar, 0, 2 * sizeof(uint32_t), stream);      // capturable (G9-ok)
    mono<<<512, 256, 0, stream>>>(x, words, W1, b1, W2, b2, W3, b3,
                                  xh, bth, sig, bar, out);
}